// Round 4
// baseline (31.096 us; speedup 1.0000x reference)
//
#include <hip/hip_runtime.h>
#include <math.h>

#define LBL 16
#define NSTATES 1024
#define B_TOTAL 32768
#define WAVES 8
#define BLOCK_THREADS (WAVES * 64)              // 512
#define COLS_PER_BLOCK 64
#define GRID_BLOCKS (B_TOTAL / COLS_PER_BLOCK)  // 512

// LDS word offsets (total 19008 words = 76032 B -> 2 blocks/CU)
#define SF1_OFF 0          // 8192 words: A1 fragments, word = ct*128 + q*64 + h*32 + 2r
#define SCM_OFF 8192       // 8256 words: S^T bf16 [l][1032 u16]
#define PB_OFF  16448      // 2560 words: per-wave P tile [w][320]
#define LDS_WORDS 19008

typedef __attribute__((ext_vector_type(8))) short bf16x8;
typedef __attribute__((ext_vector_type(4))) float f32x4;

#define LOG2E 1.4426950408889634f

#if __has_builtin(__builtin_amdgcn_exp2f)
#define EXP2F __builtin_amdgcn_exp2f
#else
#define EXP2F exp2f
#endif

static __device__ __forceinline__ unsigned short bf16_rne(float x) {
    union { float f; unsigned u; } v; v.f = x;
    unsigned r = v.u + 0x7FFFu + ((v.u >> 16) & 1u);
    return (unsigned short)(r >> 16);
}
static __device__ __forceinline__ float bf16_to_f(unsigned short h) {
    union { unsigned u; float f; } v; v.u = ((unsigned)h) << 16;
    return v.f;
}
static __device__ __forceinline__ unsigned cvt_pk_bf16(float lo, float hi) {
    unsigned r;
    asm("v_cvt_pk_bf16_f32 %0, %1, %2" : "=v"(r) : "v"(lo), "v"(hi));
    return r;
}

__global__ __launch_bounds__(BLOCK_THREADS, 4) void plm_mfma3(
    const float* __restrict__ f, const float* __restrict__ y,
    const int* __restrict__ S, float* __restrict__ out,
    float* __restrict__ block_loss, unsigned* __restrict__ cnt)
{
    __shared__ __align__(16) unsigned SH[LDS_WORDS];
    unsigned* sf1 = SH + SF1_OFF;
    unsigned short* scm = (unsigned short*)(SH + SCM_OFF);
    unsigned* pb = SH + PB_OFF;
    // post-loop overlays (Sfrag1 region is dead after the main loop)
    float* part = (float*)SH;            // [w][16][20] = 2560 words
    float* wls  = (float*)(SH + 2560);   // 8 floats
    int*   flag = (int*)(SH + 2568);

    const int tid = threadIdx.x;

    // ---- Prologue: build Scm (S^T bf16) and Sfrag1 (MFMA1 A-fragments) ----
    for (int s = tid; s < NSTATES; s += BLOCK_THREADS) {
        const int4* sp = (const int4*)(S + (size_t)s * LBL);
        int4 ra = sp[0], rb = sp[1], rc = sp[2], rd = sp[3];
        int bb[16] = { ra.x, ra.y, ra.z, ra.w, rb.x, rb.y, rb.z, rb.w,
                       rc.x, rc.y, rc.z, rc.w, rd.x, rd.y, rd.z, rd.w };
#pragma unroll
        for (int l = 0; l < LBL; ++l)
            scm[l * 1032 + s] = (unsigned short)((bb[l] > 0) ? 0x3F80u : 0u);
        const int ct = s >> 4, r = s & 15;
#pragma unroll
        for (int h = 0; h < 2; ++h)
#pragma unroll
            for (int q = 0; q < 2; ++q) {
                uint2 d;
                d.x = ((bb[8*h+4*q+0] > 0) ? 0x3F80u : 0u) | ((bb[8*h+4*q+1] > 0) ? 0x3F800000u : 0u);
                d.y = ((bb[8*h+4*q+2] > 0) ? 0x3F80u : 0u) | ((bb[8*h+4*q+3] > 0) ? 0x3F800000u : 0u);
                *(uint2*)&sf1[ct * 128 + q * 64 + h * 32 + 2 * r] = d;
            }
    }
    __syncthreads();

    // ---- Per-wave setup ----
    const int w = tid >> 6, lane = tid & 63;
    const int c = lane & 15;          // batch col within group / MFMA row index
    const int g = lane >> 4;          // lane group 0..3
    const int cg = w & 3;             // column group
    const int half = w >> 2;          // state half
    const int b = blockIdx.x * COLS_PER_BLOCK + cg * LBL + c;
    const int h = g & 1;              // label half for this lane's k-range
    const int hilo = g >> 1;          // 0: bf16 hi, 1: residual lo

    // f row (8 labels), pre-scaled by log2(e) so v_exp_f32 (2^x) applies directly
    const float4* fr = (const float4*)(f + (size_t)b * LBL + h * 8);
    float4 x0 = fr[0], x1 = fr[1];
    float xs[8] = { x0.x, x0.y, x0.z, x0.w, x1.x, x1.y, x1.z, x1.w };
#pragma unroll
    for (int j = 0; j < 8; ++j) xs[j] *= LOG2E;

    // U2 = sum of positive parts (shared shift; exp2 arg <= 0 always)
    float up = 0.f;
#pragma unroll
    for (int j = 0; j < 8; ++j) up += fmaxf(xs[j], 0.f);
    const float U2 = up + __shfl_xor(up, 16);
    const float nUb = -U2;
    const f32x4 cin = { nUb, nUb, nUb, nUb };   // bias folded into MFMA1 C-in

    // B1 fragment: k<16 -> bf16(f2), k>=16 -> bf16 residual
    union { unsigned short s[8]; bf16x8 v; } b1u;
#pragma unroll
    for (int j = 0; j < 8; ++j) {
        unsigned short hb = bf16_rne(xs[j]);
        unsigned short lb = bf16_rne(xs[j] - bf16_to_f(hb));
        b1u.s[j] = (unsigned short)(hilo ? lb : hb);
    }
    const bf16x8 b1f = b1u.v;

    unsigned* pw = pb + w * 320;
    const unsigned* sf1w = sf1 + half * 4096 + h * 32 + 2 * c;
    const unsigned short* scmw = scm + (unsigned)c * 1032 + half * 512;

    f32x4 cacc = 0.0f;
    float zacc = 0.f;

    // ---- Main loop: 16 tiles x 32 states ----
#pragma unroll
    for (int t = 0; t < 16; ++t) {
        uint2 a00 = *(const uint2*)&sf1w[t * 256 + 0];    // chunk0, q=0
        uint2 a01 = *(const uint2*)&sf1w[t * 256 + 64];   // chunk0, q=1
        uint2 a10 = *(const uint2*)&sf1w[t * 256 + 128];  // chunk1, q=0
        uint2 a11 = *(const uint2*)&sf1w[t * 256 + 192];  // chunk1, q=1
        union { unsigned u[4]; bf16x8 v; } A0, A1;
        A0.u[0] = a00.x; A0.u[1] = a00.y; A0.u[2] = a01.x; A0.u[3] = a01.y;
        A1.u[0] = a10.x; A1.u[1] = a10.y; A1.u[2] = a11.x; A1.u[3] = a11.y;

        f32x4 pot0 = __builtin_amdgcn_mfma_f32_16x16x32_bf16(A0.v, b1f, cin, 0, 0, 0);
        f32x4 pot1 = __builtin_amdgcn_mfma_f32_16x16x32_bf16(A1.v, b1f, cin, 0, 0, 0);

        float e0 = EXP2F(pot0[0]), e1 = EXP2F(pot0[1]);
        float e2 = EXP2F(pot0[2]), e3 = EXP2F(pot0[3]);
        float e4 = EXP2F(pot1[0]), e5 = EXP2F(pot1[1]);
        float e6 = EXP2F(pot1[2]), e7 = EXP2F(pot1[3]);
        zacc += ((e0 + e1) + (e2 + e3)) + ((e4 + e5) + (e6 + e7));

        uint2 pkA, pkB;
        pkA.x = cvt_pk_bf16(e0, e1); pkA.y = cvt_pk_bf16(e2, e3);
        pkB.x = cvt_pk_bf16(e4, e5); pkB.y = cvt_pk_bf16(e6, e7);
        *(uint2*)&pw[c * 20 + 2 * g] = pkA;       // chunk0: k-pairs 4g..
        *(uint2*)&pw[c * 20 + 8 + 2 * g] = pkB;   // chunk1: k-pairs 16+4g..

        bf16x8 a2 = *(const bf16x8*)&scmw[t * 32 + 8 * g];
        asm volatile("" ::: "memory");            // P writes before P read (cross-lane RAW)
        bf16x8 b2 = *(const bf16x8*)&pw[c * 20 + 4 * g];
        cacc = __builtin_amdgcn_mfma_f32_16x16x32_bf16(a2, b2, cacc, 0, 0, 0);
        asm volatile("" ::: "memory");            // next tile's P writes after this read (WAR)
    }

    // ---- Stash partials (overlay Sfrag1 region; barrier first) ----
    __syncthreads();
    *(f32x4*)&part[(w * 16 + c) * 20 + 4 * g] = cacc;
    part[(w * 16 + c) * 20 + 16 + g] = zacc;
    __syncthreads();

    // ---- Merge halves, write pMargin, per-block loss ----
    {
        const int cg2 = tid >> 7;          // 0..3
        const int c2  = (tid >> 3) & 15;   // 0..15
        const int lp  = tid & 7;           // label pair
        const int w0 = cg2, w1 = cg2 + 4;
        const int bg = blockIdx.x * COLS_PER_BLOCK + cg2 * LBL + c2;

        float z = 0.f;
#pragma unroll
        for (int gg = 0; gg < 4; ++gg)
            z += part[(w0 * 16 + c2) * 20 + 16 + gg] + part[(w1 * 16 + c2) * 20 + 16 + gg];
        const float invz = 1.0f / z;

        const float2 yv = *(const float2*)(y + (size_t)bg * LBL + 2 * lp);
        float yr[2] = { yv.x, yv.y };
        float* prow = out + 1 + (size_t)bg * LBL + 2 * lp;

        float ls = 0.f;
#pragma unroll
        for (int r2 = 0; r2 < 2; ++r2) {
            const int l = 2 * lp + r2;
            float num = part[(w0 * 16 + c2) * 20 + l] + part[(w1 * 16 + c2) * 20 + l];
            float p = num * invz;
            prow[r2] = p;
            float gv = yr[r2];
            float fid = sqrtf(fmaf(p, gv, 1e-8f)) + sqrtf(fmaf(1.f - p, 1.f - gv, 1e-8f));
            float pt = fmaf(p, gv, (1.f - p) * (1.f - gv));
            float at = fmaf(0.75f, gv, 0.25f * (1.f - gv));
            float om = 1.f - pt;
            ls += (1.f - fid) * at * om * om;
        }
#pragma unroll
        for (int off = 32; off; off >>= 1) ls += __shfl_down(ls, off);
        if (lane == 0) wls[w] = ls;
    }
    __syncthreads();

    // ---- Fused deterministic loss reduce: last-done block sums all ----
    if (tid == 0) {
        float t = 0.f;
#pragma unroll
        for (int i = 0; i < WAVES; ++i) t += wls[i];
        __hip_atomic_store(&block_loss[blockIdx.x], t, __ATOMIC_RELAXED, __HIP_MEMORY_SCOPE_AGENT);
        unsigned old = __hip_atomic_fetch_add(cnt, 1u, __ATOMIC_ACQ_REL, __HIP_MEMORY_SCOPE_AGENT);
        *flag = (old == (unsigned)(GRID_BLOCKS - 1)) ? 1 : 0;
    }
    __syncthreads();
    if (*flag && tid < 64) {
        float s = 0.f;
        for (int i = tid; i < GRID_BLOCKS; i += 64)
            s += __hip_atomic_load(&block_loss[i], __ATOMIC_RELAXED, __HIP_MEMORY_SCOPE_AGENT);
#pragma unroll
        for (int off = 32; off; off >>= 1) s += __shfl_down(s, off);
        if (tid == 0) out[0] = s * (1.0f / ((float)B_TOTAL * (float)LBL));
    }
}

extern "C" void kernel_launch(void* const* d_in, const int* in_sizes, int n_in,
                              void* d_out, int out_size, void* d_ws, size_t ws_size,
                              hipStream_t stream) {
    const float* f = (const float*)d_in[0];   // [B, 16]
    const float* y = (const float*)d_in[1];   // [B, 16]
    const int*   S = (const int*)d_in[2];     // [1024, 16]
    float* out = (float*)d_out;               // [0]=loss, [1..]=pMargin
    float* bl  = (float*)d_ws;                // 512 block partials
    unsigned* cnt = (unsigned*)((char*)d_ws + GRID_BLOCKS * sizeof(float));

    hipMemsetAsync(cnt, 0, sizeof(unsigned), stream);  // reset finisher counter each launch
    plm_mfma3<<<GRID_BLOCKS, BLOCK_THREADS, 0, stream>>>(f, y, S, out, bl, cnt);
}

// Round 6
// 20.492 us; speedup vs baseline: 1.5175x; 1.5175x over previous
//
#include <hip/hip_runtime.h>
#include <math.h>

#define LBL 16
#define B_TOTAL 32768
#define WAVES 8
#define BLOCK_THREADS (WAVES * 64)              // 512
#define COLS_PER_BLOCK 64
#define GRID_BLOCKS (B_TOTAL / COLS_PER_BLOCK)  // 512

// LDS u32-word offsets. Total 20480 words = 81920 B = exactly half of 160 KiB
// -> 2 blocks/CU -> 4 waves/SIMD.
// [0,8192)      U:   U[s][l] bf16(bit) table, 1024 x 16 u16 (32 KB)
// [8192,16384)  scm: [l][ pair ^ ((l&3)<<2) ] u32 (2 states/word), 16 x 512 (32 KB)
// [16384,20480) P:   [w][buf][c][ pair ^ ((c&3)<<2) ], 8 x 2 x 256 u32 (16 KB)
#define SCM_WOFF 8192
#define P_WOFF   16384
#define LDS_WORDS 20480

typedef __attribute__((ext_vector_type(8))) short bf16x8;
typedef __attribute__((ext_vector_type(4))) float f32x4;

#define LOG2E 1.4426950408889634f

#if __has_builtin(__builtin_amdgcn_exp2f)
#define EXP2F __builtin_amdgcn_exp2f
#else
#define EXP2F exp2f
#endif

static __device__ __forceinline__ unsigned short bf16_rne(float x) {
    union { float f; unsigned u; } v; v.f = x;
    unsigned r = v.u + 0x7FFFu + ((v.u >> 16) & 1u);
    return (unsigned short)(r >> 16);
}
static __device__ __forceinline__ float bf16_to_f(unsigned short h) {
    union { unsigned u; float f; } v; v.u = ((unsigned)h) << 16;
    return v.f;
}
static __device__ __forceinline__ unsigned cvt_pk_bf16(float lo, float hi) {
    unsigned r;
    asm("v_cvt_pk_bf16_f32 %0, %1, %2" : "=v"(r) : "v"(lo), "v"(hi));
    return r;
}

#define PKB(p, q) ((((p) > 0) ? 0x3F80u : 0u) | (((q) > 0) ? 0x3F800000u : 0u))

__global__ __launch_bounds__(BLOCK_THREADS, 4) void plm_mfma5(
    const float* __restrict__ f, const float* __restrict__ y,
    const int* __restrict__ S, float* __restrict__ out,
    float* __restrict__ block_loss)
{
    __shared__ __align__(16) unsigned SH[LDS_WORDS];
    unsigned short* U16 = (unsigned short*)SH;     // U[s][l]: bf16(bit) table, 1024x16
    // post-main-loop overlays (U region dead after the loop)
    float* part = (float*)SH;                      // [w][16][20] = 2560 floats
    float* wls  = (float*)(SH + 2560);

    const int tid = threadIdx.x;

    // ---------------- Prologue: one thread : two consecutive states ----------------
    {
        const int s0 = tid * 2;
        int b0[16], b1[16];
        {
            const int4* sp = (const int4*)(S + (size_t)s0 * LBL);
            int4 a = sp[0], bq = sp[1], cq = sp[2], dq = sp[3];
            b0[0]=a.x;  b0[1]=a.y;  b0[2]=a.z;  b0[3]=a.w;
            b0[4]=bq.x; b0[5]=bq.y; b0[6]=bq.z; b0[7]=bq.w;
            b0[8]=cq.x; b0[9]=cq.y; b0[10]=cq.z;b0[11]=cq.w;
            b0[12]=dq.x;b0[13]=dq.y;b0[14]=dq.z;b0[15]=dq.w;
        }
        {
            const int4* sp = (const int4*)(S + (size_t)(s0 + 1) * LBL);
            int4 a = sp[0], bq = sp[1], cq = sp[2], dq = sp[3];
            b1[0]=a.x;  b1[1]=a.y;  b1[2]=a.z;  b1[3]=a.w;
            b1[4]=bq.x; b1[5]=bq.y; b1[6]=bq.z; b1[7]=bq.w;
            b1[8]=cq.x; b1[9]=cq.y; b1[10]=cq.z;b1[11]=cq.w;
            b1[12]=dq.x;b1[13]=dq.y;b1[14]=dq.z;b1[15]=dq.w;
        }
        // U rows: 2x ds_write_b128 per state
        uint4 ua = { PKB(b0[0],b0[1]),  PKB(b0[2],b0[3]),  PKB(b0[4],b0[5]),  PKB(b0[6],b0[7]) };
        uint4 ub = { PKB(b0[8],b0[9]),  PKB(b0[10],b0[11]),PKB(b0[12],b0[13]),PKB(b0[14],b0[15]) };
        uint4 uc = { PKB(b1[0],b1[1]),  PKB(b1[2],b1[3]),  PKB(b1[4],b1[5]),  PKB(b1[6],b1[7]) };
        uint4 ud = { PKB(b1[8],b1[9]),  PKB(b1[10],b1[11]),PKB(b1[12],b1[13]),PKB(b1[14],b1[15]) };
        *(uint4*)&U16[s0 * 16]          = ua;
        *(uint4*)&U16[s0 * 16 + 8]      = ub;
        *(uint4*)&U16[(s0 + 1) * 16]    = uc;
        *(uint4*)&U16[(s0 + 1) * 16 + 8]= ud;
        // scm: both states packed per label, XOR-swizzled pair index (pair = tid)
#pragma unroll
        for (int l = 0; l < 16; ++l) {
            unsigned v = (((b0[l] > 0) ? 0x3F80u : 0u)) | (((b1[l] > 0) ? 0x3F800000u : 0u));
            SH[SCM_WOFF + l * 512 + ((unsigned)tid ^ ((unsigned)(l & 3) << 2))] = v;
        }
    }
    __syncthreads();

    // ---------------- Per-wave setup ----------------
    const int w = tid >> 6, lane = tid & 63;
    const int c = lane & 15;          // batch col within group / MFMA row index
    const int g = lane >> 4;          // lane group 0..3
    const int cg = w & 3;             // column group
    const int half = w >> 2;          // state half
    const int b = blockIdx.x * COLS_PER_BLOCK + cg * LBL + c;
    const int h = g & 1;              // label half for this lane's k-range
    const int hilo = g >> 1;          // 0: bf16 hi of f2, 1: residual lo

    // f row (8 labels), pre-scaled by log2(e) so v_exp_f32 (2^x) applies directly
    const float4* fr = (const float4*)(f + (size_t)b * LBL + h * 8);
    float4 x0 = fr[0], x1 = fr[1];
    float xs[8] = { x0.x, x0.y, x0.z, x0.w, x1.x, x1.y, x1.z, x1.w };
#pragma unroll
    for (int j = 0; j < 8; ++j) xs[j] *= LOG2E;

    // U2 = sum of positive parts (shared shift; exp2 arg <= ~0 always)
    float up = 0.f;
#pragma unroll
    for (int j = 0; j < 8; ++j) up += fmaxf(xs[j], 0.f);
    const float U2 = up + __shfl_xor(up, 16);
    const float nUb = -U2;
    const f32x4 cin = { nUb, nUb, nUb, nUb };   // bias folded into MFMA1 C-in

    // B1 fragment: k<16 -> bf16(f2), k>=16 -> bf16 residual
    union { unsigned short s[8]; bf16x8 v; } b1u;
#pragma unroll
    for (int j = 0; j < 8; ++j) {
        unsigned short hb = bf16_rne(xs[j]);
        unsigned short lb = bf16_rne(xs[j] - bf16_to_f(hb));
        b1u.s[j] = (unsigned short)(hilo ? lb : hb);
    }
    const bf16x8 b1f = b1u.v;

    // Per-lane byte bases (all loop addressing folds to immediate offsets).
    // NOTE: byte bases derived from the word-offset macros (R5's bug was a
    // hand-typed 65536 here, which aliased the P region).
    const unsigned gc = (unsigned)(g ^ (c & 3));
    const char* baseA  = (const char*)SH + half * 16384 + 32 * c + 16 * h;  // U region
    const char* baseS2 = (const char*)SH + SCM_WOFF * 4 + 2048 * c + 1024 * half + 16 * gc;
    unsigned* pwB = SH + P_WOFF + w * 512;                                  // 2 bufs x 256 u32
    const char* basePr = (const char*)pwB + 64 * c + 16 * gc;               // P read base
    const unsigned k2 = ((unsigned)c & 3u) << 2;
    const unsigned pw0 = (unsigned)c * 16u + (((unsigned)(2 * g)) ^ k2);    // q0 pair base
    const unsigned pw1 = (unsigned)c * 16u + (((unsigned)(8 + 2 * g)) ^ k2);// q1 pair base

    f32x4 cacc = 0.0f;
    float zacc = 0.f;

    // ---- produce: 2x A1 ds_read_b128 -> 2x MFMA1 (bias in C) -> exp2 -> pack -> P tile ----
    auto produce = [&](int t, int buf) {
        const char* pa = baseA + t * 1024;
        bf16x8 A0 = *(const bf16x8*)(pa);        // chunk q=0
        bf16x8 A1 = *(const bf16x8*)(pa + 512);  // chunk q=1
        f32x4 pot0 = __builtin_amdgcn_mfma_f32_16x16x32_bf16(A0, b1f, cin, 0, 0, 0);
        f32x4 pot1 = __builtin_amdgcn_mfma_f32_16x16x32_bf16(A1, b1f, cin, 0, 0, 0);
        float e0 = EXP2F(pot0[0]), e1 = EXP2F(pot0[1]);
        float e2 = EXP2F(pot0[2]), e3 = EXP2F(pot0[3]);
        float e4 = EXP2F(pot1[0]), e5 = EXP2F(pot1[1]);
        float e6 = EXP2F(pot1[2]), e7 = EXP2F(pot1[3]);
        zacc += ((e0 + e1) + (e2 + e3)) + ((e4 + e5) + (e6 + e7));
        uint2 pkA, pkB;
        pkA.x = cvt_pk_bf16(e0, e1); pkA.y = cvt_pk_bf16(e2, e3);
        pkB.x = cvt_pk_bf16(e4, e5); pkB.y = cvt_pk_bf16(e6, e7);
        unsigned* pd = pwB + buf * 256;
        *(uint2*)&pd[pw0] = pkA;
        *(uint2*)&pd[pw1] = pkB;
    };
    // ---- consume: scm fragment + P fragment -> MFMA2 accumulate ----
    auto consume = [&](int t, int buf) {
        bf16x8 a2 = *(const bf16x8*)(baseS2 + t * 64);
        bf16x8 b2 = *(const bf16x8*)(basePr + buf * 1024);
        cacc = __builtin_amdgcn_mfma_f32_16x16x32_bf16(a2, b2, cacc, 0, 0, 0);
    };

    // ---- Main loop, software-pipelined with double-buffered P (R3-proven order) ----
    produce(0, 0);
#pragma unroll
    for (int tp = 0; tp < 7; ++tp) {
        produce(2 * tp + 1, 1); consume(2 * tp,     0);
        produce(2 * tp + 2, 0); consume(2 * tp + 1, 1);
    }
    produce(15, 1); consume(14, 0);
    consume(15, 1);

    // ---- Stash partials into overlay (U region dead); barrier protects reuse ----
    __syncthreads();
    *(f32x4*)&part[(w * 16 + c) * 20 + 4 * g] = cacc;
    part[(w * 16 + c) * 20 + 16 + g] = zacc;
    __syncthreads();

    // ---- Merge halves, write pMargin, per-block loss ----
    {
        const int cg2 = tid >> 7;          // 0..3
        const int c2  = (tid >> 3) & 15;   // 0..15
        const int lp  = tid & 7;           // label pair
        const int w0 = cg2, w1 = cg2 + 4;
        const int bg = blockIdx.x * COLS_PER_BLOCK + cg2 * LBL + c2;

        float z = 0.f;
#pragma unroll
        for (int gg = 0; gg < 4; ++gg)
            z += part[(w0 * 16 + c2) * 20 + 16 + gg] + part[(w1 * 16 + c2) * 20 + 16 + gg];
        const float invz = 1.0f / z;

        const float2 yv = *(const float2*)(y + (size_t)bg * LBL + 2 * lp);
        float yr[2] = { yv.x, yv.y };
        float* prow = out + 1 + (size_t)bg * LBL + 2 * lp;

        float ls = 0.f;
#pragma unroll
        for (int r2 = 0; r2 < 2; ++r2) {
            const int l = 2 * lp + r2;
            float num = part[(w0 * 16 + c2) * 20 + l] + part[(w1 * 16 + c2) * 20 + l];
            float p = num * invz;
            prow[r2] = p;
            float gv = yr[r2];
            float fid = sqrtf(fmaf(p, gv, 1e-8f)) + sqrtf(fmaf(1.f - p, 1.f - gv, 1e-8f));
            float pt = fmaf(p, gv, (1.f - p) * (1.f - gv));
            float at = fmaf(0.75f, gv, 0.25f * (1.f - gv));
            float om = 1.f - pt;
            ls += (1.f - fid) * at * om * om;
        }
#pragma unroll
        for (int off = 32; off; off >>= 1) ls += __shfl_down(ls, off);
        if (lane == 0) wls[w] = ls;
    }
    __syncthreads();
    if (tid == 0) {
        float t = 0.f;
#pragma unroll
        for (int i = 0; i < WAVES; ++i) t += wls[i];
        block_loss[blockIdx.x] = t;
    }
}

__global__ __launch_bounds__(256) void plm_reduce(
    const float* __restrict__ block_loss, int n, float* __restrict__ out)
{
    __shared__ float wsum[4];
    float s = 0.f;
    for (int i = threadIdx.x; i < n; i += 256) s += block_loss[i];
#pragma unroll
    for (int off = 32; off; off >>= 1) s += __shfl_down(s, off);
    const int wave = threadIdx.x >> 6;
    if ((threadIdx.x & 63) == 0) wsum[wave] = s;
    __syncthreads();
    if (threadIdx.x == 0) {
        float t = (wsum[0] + wsum[1]) + (wsum[2] + wsum[3]);
        out[0] = t * (1.0f / ((float)B_TOTAL * (float)LBL));
    }
}

extern "C" void kernel_launch(void* const* d_in, const int* in_sizes, int n_in,
                              void* d_out, int out_size, void* d_ws, size_t ws_size,
                              hipStream_t stream) {
    const float* f = (const float*)d_in[0];   // [B, 16]
    const float* y = (const float*)d_in[1];   // [B, 16]
    const int*   S = (const int*)d_in[2];     // [1024, 16]
    float* out = (float*)d_out;               // [0]=loss, [1..]=pMargin
    float* bl  = (float*)d_ws;                // 512 block partials

    plm_mfma5<<<GRID_BLOCKS, BLOCK_THREADS, 0, stream>>>(f, y, S, out, bl);
    plm_reduce<<<1, 256, 0, stream>>>(bl, GRID_BLOCKS, out);
}

// Round 7
// 18.005 us; speedup vs baseline: 1.7271x; 1.1381x over previous
//
#include <hip/hip_runtime.h>
#include <math.h>

#define LBL 16
#define B_TOTAL 32768
#define WAVES 8
#define BLOCK_THREADS (WAVES * 64)              // 512
#define COLS_PER_BLOCK 64
#define GRID_BLOCKS (B_TOTAL / COLS_PER_BLOCK)  // 512

// LDS u32-word offsets. Total 16448 words = 65792 B -> easy 2 blocks/CU.
// [0,8192)       U: A1 fragment table, 1024 slots x 32B, permuted state->row
//                   (slot = half*512 + t*32 + q*16 + x; state o=16a+8b+4q+r -> x=8a+4b+r)
// [8192,16448)   scm: [l][pair ^ ((l&3)<<2)] u32, row stride 516 words (2064B;
//                   516 % 32 == 4 spreads lanes across all bank quads)
#define SCM_WOFF 8192
#define SCM_STRIDE 516
#define LDS_WORDS (SCM_WOFF + LBL * SCM_STRIDE)   // 16448

typedef __attribute__((ext_vector_type(8))) short bf16x8;
typedef __attribute__((ext_vector_type(4))) float f32x4;

#define LOG2E 1.4426950408889634f

#if __has_builtin(__builtin_amdgcn_exp2f)
#define EXP2F __builtin_amdgcn_exp2f
#else
#define EXP2F exp2f
#endif

static __device__ __forceinline__ unsigned short bf16_rne(float x) {
    union { float f; unsigned u; } v; v.f = x;
    unsigned r = v.u + 0x7FFFu + ((v.u >> 16) & 1u);
    return (unsigned short)(r >> 16);
}
static __device__ __forceinline__ float bf16_to_f(unsigned short h) {
    union { unsigned u; float f; } v; v.u = ((unsigned)h) << 16;
    return v.f;
}
static __device__ __forceinline__ unsigned cvt_pk_bf16(float lo, float hi) {
    unsigned r;
    asm("v_cvt_pk_bf16_f32 %0, %1, %2" : "=v"(r) : "v"(lo), "v"(hi));
    return r;
}

#define PKB(p, q) ((((p) > 0) ? 0x3F80u : 0u) | (((q) > 0) ? 0x3F800000u : 0u))

__global__ __launch_bounds__(BLOCK_THREADS, 4) void plm_mfma6(
    const float* __restrict__ f, const float* __restrict__ y,
    const int* __restrict__ S, float* __restrict__ out,
    float* __restrict__ block_loss)
{
    __shared__ __align__(16) unsigned SH[LDS_WORDS];
    unsigned short* U16 = (unsigned short*)SH;     // A1 fragment table
    // post-main-loop overlays (U region dead after the loop)
    float* part = (float*)SH;                      // [w][16][20] = 2560 floats
    float* wls  = (float*)(SH + 2560);

    const int tid = threadIdx.x;

    // ---------------- Prologue: one thread : two consecutive states ----------------
    {
        const int s0 = tid * 2;
        int b0[16], b1[16];
        {
            const int4* sp = (const int4*)(S + (size_t)s0 * LBL);
            int4 a = sp[0], bq = sp[1], cq = sp[2], dq = sp[3];
            b0[0]=a.x;  b0[1]=a.y;  b0[2]=a.z;  b0[3]=a.w;
            b0[4]=bq.x; b0[5]=bq.y; b0[6]=bq.z; b0[7]=bq.w;
            b0[8]=cq.x; b0[9]=cq.y; b0[10]=cq.z;b0[11]=cq.w;
            b0[12]=dq.x;b0[13]=dq.y;b0[14]=dq.z;b0[15]=dq.w;
        }
        {
            const int4* sp = (const int4*)(S + (size_t)(s0 + 1) * LBL);
            int4 a = sp[0], bq = sp[1], cq = sp[2], dq = sp[3];
            b1[0]=a.x;  b1[1]=a.y;  b1[2]=a.z;  b1[3]=a.w;
            b1[4]=bq.x; b1[5]=bq.y; b1[6]=bq.z; b1[7]=bq.w;
            b1[8]=cq.x; b1[9]=cq.y; b1[10]=cq.z;b1[11]=cq.w;
            b1[12]=dq.x;b1[13]=dq.y;b1[14]=dq.z;b1[15]=dq.w;
        }
        // Permuted slot: state o = 16a+8b+4q+r goes to chunk q, row x = 8a+4b+r.
        // This makes MFMA1's C-layout coincide with MFMA2's B-layout (k == o),
        // so P never touches LDS. s0 even -> s0+1 lands at slot+1.
        const int half_s = s0 >> 9, tt = (s0 >> 5) & 15, o = s0 & 31;
        const int q = (o >> 2) & 1;
        const int x = ((o >> 4) & 1) * 8 + ((o >> 3) & 1) * 4 + (o & 3);
        const int slot = half_s * 512 + tt * 32 + q * 16 + x;
        unsigned short* Urow = U16 + slot * 16;
        uint4 ua = { PKB(b0[0],b0[1]),  PKB(b0[2],b0[3]),  PKB(b0[4],b0[5]),  PKB(b0[6],b0[7]) };
        uint4 ub = { PKB(b0[8],b0[9]),  PKB(b0[10],b0[11]),PKB(b0[12],b0[13]),PKB(b0[14],b0[15]) };
        uint4 uc = { PKB(b1[0],b1[1]),  PKB(b1[2],b1[3]),  PKB(b1[4],b1[5]),  PKB(b1[6],b1[7]) };
        uint4 ud = { PKB(b1[8],b1[9]),  PKB(b1[10],b1[11]),PKB(b1[12],b1[13]),PKB(b1[14],b1[15]) };
        *(uint4*)&Urow[0]  = ua;
        *(uint4*)&Urow[8]  = ub;
        *(uint4*)&Urow[16] = uc;
        *(uint4*)&Urow[24] = ud;
        // scm: both states packed per label, XOR-swizzled pair index (pair = tid)
#pragma unroll
        for (int l = 0; l < 16; ++l) {
            unsigned v = (((b0[l] > 0) ? 0x3F80u : 0u)) | (((b1[l] > 0) ? 0x3F800000u : 0u));
            SH[SCM_WOFF + l * SCM_STRIDE + ((unsigned)tid ^ ((unsigned)(l & 3) << 2))] = v;
        }
    }
    __syncthreads();

    // ---------------- Per-wave setup ----------------
    const int w = tid >> 6, lane = tid & 63;
    const int c = lane & 15;          // batch col within group / MFMA row index
    const int g = lane >> 4;          // lane group 0..3
    const int cg = w & 3;             // column group
    const int half = w >> 2;          // state half
    const int b = blockIdx.x * COLS_PER_BLOCK + cg * LBL + c;
    const int h = g & 1;              // label half for this lane's k-range
    const int hilo = g >> 1;          // 0: bf16 hi of f2, 1: residual lo

    // f row (8 labels), pre-scaled by log2(e) so v_exp_f32 (2^x) applies directly
    const float4* fr = (const float4*)(f + (size_t)b * LBL + h * 8);
    float4 x0 = fr[0], x1 = fr[1];
    float xs[8] = { x0.x, x0.y, x0.z, x0.w, x1.x, x1.y, x1.z, x1.w };
#pragma unroll
    for (int j = 0; j < 8; ++j) xs[j] *= LOG2E;

    // U2 = sum of positive parts (shared shift; exp2 arg <= ~0 always)
    float up = 0.f;
#pragma unroll
    for (int j = 0; j < 8; ++j) up += fmaxf(xs[j], 0.f);
    const float U2 = up + __shfl_xor(up, 16);
    const float nUb = -U2;
    const f32x4 cin = { nUb, nUb, nUb, nUb };   // bias folded into MFMA1 C-in

    // B1 fragment: k<16 -> bf16(f2), k>=16 -> bf16 residual
    union { unsigned short s[8]; bf16x8 v; } b1u;
#pragma unroll
    for (int j = 0; j < 8; ++j) {
        unsigned short hb = bf16_rne(xs[j]);
        unsigned short lb = bf16_rne(xs[j] - bf16_to_f(hb));
        b1u.s[j] = (unsigned short)(hilo ? lb : hb);
    }
    const bf16x8 b1f = b1u.v;

    // Per-lane byte bases (loop addressing folds to immediate offsets)
    const unsigned gc = (unsigned)(g ^ (c & 3));
    const char* baseA  = (const char*)SH + half * 16384 + 32 * c + 16 * h;
    const char* baseS2 = (const char*)SH + SCM_WOFF * 4 + 2064 * c + 1024 * half + 16 * gc;

    f32x4 cacc = 0.0f;
    float zacc = 0.f;

    // ---- Main loop: 16 tiles x 32 states, all dataflow through registers ----
#pragma unroll
    for (int t = 0; t < 16; ++t) {
        const char* pa = baseA + t * 1024;
        bf16x8 A0 = *(const bf16x8*)(pa);          // chunk q=0 (permuted rows)
        bf16x8 A1 = *(const bf16x8*)(pa + 512);    // chunk q=1
        bf16x8 a2 = *(const bf16x8*)(baseS2 + t * 64);  // independent: issues early

        f32x4 pot0 = __builtin_amdgcn_mfma_f32_16x16x32_bf16(A0, b1f, cin, 0, 0, 0);
        f32x4 pot1 = __builtin_amdgcn_mfma_f32_16x16x32_bf16(A1, b1f, cin, 0, 0, 0);

        float e0 = EXP2F(pot0[0]), e1 = EXP2F(pot0[1]);
        float e2 = EXP2F(pot0[2]), e3 = EXP2F(pot0[3]);
        float e4 = EXP2F(pot1[0]), e5 = EXP2F(pot1[1]);
        float e6 = EXP2F(pot1[2]), e7 = EXP2F(pot1[3]);
        zacc += ((e0 + e1) + (e2 + e3)) + ((e4 + e5) + (e6 + e7));

        // Producer lane == consumer lane: B2 fragment assembled in registers.
        // element j = 4q+r  ->  k = o (state offset) by construction.
        union { unsigned u[4]; bf16x8 v; } b2;
        b2.u[0] = cvt_pk_bf16(e0, e1);
        b2.u[1] = cvt_pk_bf16(e2, e3);
        b2.u[2] = cvt_pk_bf16(e4, e5);
        b2.u[3] = cvt_pk_bf16(e6, e7);

        cacc = __builtin_amdgcn_mfma_f32_16x16x32_bf16(a2, b2.v, cacc, 0, 0, 0);
    }

    // ---- Stash partials into overlay (U region dead); barrier protects reuse ----
    __syncthreads();
    *(f32x4*)&part[(w * 16 + c) * 20 + 4 * g] = cacc;
    part[(w * 16 + c) * 20 + 16 + g] = zacc;
    __syncthreads();

    // ---- Merge halves, write pMargin, per-block loss ----
    {
        const int cg2 = tid >> 7;          // 0..3
        const int c2  = (tid >> 3) & 15;   // 0..15
        const int lp  = tid & 7;           // label pair
        const int w0 = cg2, w1 = cg2 + 4;
        const int bg = blockIdx.x * COLS_PER_BLOCK + cg2 * LBL + c2;

        float z = 0.f;
#pragma unroll
        for (int gg = 0; gg < 4; ++gg)
            z += part[(w0 * 16 + c2) * 20 + 16 + gg] + part[(w1 * 16 + c2) * 20 + 16 + gg];
        const float invz = 1.0f / z;

        const float2 yv = *(const float2*)(y + (size_t)bg * LBL + 2 * lp);
        float yr[2] = { yv.x, yv.y };
        float* prow = out + 1 + (size_t)bg * LBL + 2 * lp;

        float ls = 0.f;
#pragma unroll
        for (int r2 = 0; r2 < 2; ++r2) {
            const int l = 2 * lp + r2;
            float num = part[(w0 * 16 + c2) * 20 + l] + part[(w1 * 16 + c2) * 20 + l];
            float p = num * invz;
            prow[r2] = p;
            float gv = yr[r2];
            float fid = sqrtf(fmaf(p, gv, 1e-8f)) + sqrtf(fmaf(1.f - p, 1.f - gv, 1e-8f));
            float pt = fmaf(p, gv, (1.f - p) * (1.f - gv));
            float at = fmaf(0.75f, gv, 0.25f * (1.f - gv));
            float om = 1.f - pt;
            ls += (1.f - fid) * at * om * om;
        }
#pragma unroll
        for (int off = 32; off; off >>= 1) ls += __shfl_down(ls, off);
        if (lane == 0) wls[w] = ls;
    }
    __syncthreads();
    if (tid == 0) {
        float t = 0.f;
#pragma unroll
        for (int i = 0; i < WAVES; ++i) t += wls[i];
        block_loss[blockIdx.x] = t;
    }
}

__global__ __launch_bounds__(256) void plm_reduce(
    const float* __restrict__ block_loss, int n, float* __restrict__ out)
{
    __shared__ float wsum[4];
    float s = 0.f;
    for (int i = threadIdx.x; i < n; i += 256) s += block_loss[i];
#pragma unroll
    for (int off = 32; off; off >>= 1) s += __shfl_down(s, off);
    const int wave = threadIdx.x >> 6;
    if ((threadIdx.x & 63) == 0) wsum[wave] = s;
    __syncthreads();
    if (threadIdx.x == 0) {
        float t = (wsum[0] + wsum[1]) + (wsum[2] + wsum[3]);
        out[0] = t * (1.0f / ((float)B_TOTAL * (float)LBL));
    }
}

extern "C" void kernel_launch(void* const* d_in, const int* in_sizes, int n_in,
                              void* d_out, int out_size, void* d_ws, size_t ws_size,
                              hipStream_t stream) {
    const float* f = (const float*)d_in[0];   // [B, 16]
    const float* y = (const float*)d_in[1];   // [B, 16]
    const int*   S = (const int*)d_in[2];     // [1024, 16]
    float* out = (float*)d_out;               // [0]=loss, [1..]=pMargin
    float* bl  = (float*)d_ws;                // 512 block partials

    plm_mfma6<<<GRID_BLOCKS, BLOCK_THREADS, 0, stream>>>(f, y, S, out, bl);
    plm_reduce<<<1, 256, 0, stream>>>(bl, GRID_BLOCKS, out);
}